// Round 20
// baseline (533.038 us; speedup 1.0000x reference)
//
#include <hip/hip_runtime.h>
#include <math.h>
#include <stdint.h>

// Problem constants
// B=4 S=2048 D=1024 N_NEURONS=512 K=8 N_BASIS=32 R=512 H=8 dh=64
// tokens T = 8192

typedef __attribute__((ext_vector_type(4))) float f32x4;
typedef __attribute__((ext_vector_type(8))) short s16x8;
typedef __attribute__((ext_vector_type(4))) short s16x4;
typedef __attribute__((ext_vector_type(4))) int i32x4;
typedef __attribute__((ext_vector_type(8))) int i32x8;

#define DEV __device__ __forceinline__

DEV short f2bf(float f){
  union { float f; unsigned u; } c; c.f = f;
  unsigned u = c.u;
  unsigned r = (u + 0x7fffu + ((u >> 16) & 1u)) >> 16;
  return (short)r;
}
DEV float bf2f(short s){
  union { unsigned u; float f; } c; c.u = ((unsigned)(unsigned short)s) << 16;
  return c.f;
}
DEV int pack2bf(float a, float b){
  return (int)(unsigned short)f2bf(a) | (((int)(unsigned short)f2bf(b)) << 16);
}
// f32 -> OCP e4m3fn (RNE, clamp to 448, subnormals to 2^-9 units)
DEV unsigned char f2e4m3(float f){
  union { float f; unsigned u; } c; c.f = f;
  unsigned u = c.u;
  unsigned sign = (u >> 24) & 0x80u;
  unsigned a = u & 0x7fffffffu;
  if (a >= 0x43e00000u) return (unsigned char)(sign | 0x7Eu);
  if (a < 0x3c800000u){
    union { unsigned u; float f; } d; d.u = a;
    int q = (int)(d.f * 512.0f + 0.5f);
    return (unsigned char)(sign | (unsigned)q);
  }
  unsigned m = a & 0x7fffffu;
  unsigned e = (a >> 23) - 120u;
  unsigned keep = m >> 20;
  unsigned rest = m & 0xFFFFFu;
  if (rest > 0x80000u || (rest == 0x80000u && (keep & 1u))){
    keep++;
    if (keep == 8u){ keep = 0; e++; }
  }
  if (e >= 16u || (e == 15u && keep == 7u)) return (unsigned char)(sign | 0x7Eu);
  return (unsigned char)(sign | (e << 3) | keep);
}

typedef __attribute__((address_space(3))) void lds_vt;
typedef const __attribute__((address_space(1))) void g_vt;
DEV void gload16(const void* g, void* lds){
  __builtin_amdgcn_global_load_lds((g_vt*)g, (lds_vt*)lds, 16, 0, 0);
}

// K-granule slot permutation within each 128B k-group (applied to BOTH operands
// -> k-relabeling, sum invariant). slot(c) = c<4 ? 2c : 2(c-4)+1.
DEV int gslot(int c){ return (c < 4) ? (c << 1) : (((c - 4) << 1) + 1); }

// ---------------- fused conversions: x -> {Xb bf16, Xf8 fp8 slot-permuted}; Wo,Wrt -> bf16 ----------------
__global__ void k_conv_xw(const float* __restrict__ x, short* __restrict__ Xb, char* __restrict__ Xf8,
                          const float* __restrict__ Wo, const float* __restrict__ Wrt,
                          short* __restrict__ Wob, short* __restrict__ Wrtb){
  int t = blockIdx.x*256 + threadIdx.x;   // 786432 tasks
  if (t < 524288){
    size_t d = (size_t)t * 16;
    const float4* s = (const float4*)(x + d);
    float vals[16];
    #pragma unroll
    for (int q=0;q<4;q++){ float4 v = s[q]; vals[q*4]=v.x; vals[q*4+1]=v.y; vals[q*4+2]=v.z; vals[q*4+3]=v.w; }
    s16x8 ob0, ob1;
    unsigned long long v0 = 0, v1 = 0;
    #pragma unroll
    for (int e=0;e<8;e++){
      ob0[e] = f2bf(vals[e]);
      ob1[e] = f2bf(vals[8+e]);
      v0 |= ((unsigned long long)f2e4m3(vals[e]))   << (8*e);
      v1 |= ((unsigned long long)f2e4m3(vals[8+e])) << (8*e);
    }
    *(s16x8*)(Xb + d) = ob0;
    *(s16x8*)(Xb + d + 8) = ob1;
    int c = t & 7;
    char* dst = Xf8 + (d & ~(size_t)127) + (gslot(c) << 4);
    *(unsigned long long*)dst = v0;
    *(unsigned long long*)(dst + 8) = v1;
  } else {
    int i = t - 524288;                   // 262144 float4 tasks
    const float* src = (i < 131072) ? Wo : Wrt;
    short* dst = (i < 131072) ? Wob : Wrtb;
    int j = (i < 131072) ? i : (i - 131072);
    float4 v = ((const float4*)src)[j];
    s16x4 o; o[0]=f2bf(v.x); o[1]=f2bf(v.y); o[2]=f2bf(v.z); o[3]=f2bf(v.w);
    ((s16x4*)dst)[j] = o;
  }
}

// ---------------- basis [32][1024][512] -> B2f fp8 [16384][1024], row c=r*32+n, slot-permuted ----------------
__global__ __launch_bounds__(256) void k_conv_basis8(const float* __restrict__ basis, char* __restrict__ B2f){
  __shared__ float tile[64][65];
  int tid = threadIdx.x;
  int r0 = blockIdx.x<<6, d0 = blockIdx.y<<6, n = blockIdx.z;
  const float* src = basis + ((size_t)n*1024 + d0)*512 + r0;
  for (int i = tid; i < 4096; i += 256){ int dd = i>>6, rr = i&63; tile[dd][rr] = src[(size_t)dd*512 + rr]; }
  __syncthreads();
  int rr = tid >> 2, j = tid & 3;
  unsigned long long v0 = 0, v1 = 0;
  #pragma unroll
  for (int e=0;e<8;e++){
    v0 |= ((unsigned long long)f2e4m3(tile[j*16+e][rr]))   << (8*e);
    v1 |= ((unsigned long long)f2e4m3(tile[j*16+8+e][rr])) << (8*e);
  }
  int c = j + ((d0 >> 4) & 4);
  char* dst = B2f + ((size_t)(r0+rr)*32 + n)*1024 + (size_t)(d0 & ~127) + (gslot(c) << 4);
  *(unsigned long long*)dst = v0;
  *(unsigned long long*)(dst + 8) = v1;
}

// ---------------- bf16 MFMA GEMM 128x128xBK64 -> f32 C (scores, W_o) ----------------
__global__ __launch_bounds__(256) void k_gemm_c32(
    const short* __restrict__ A, const short* __restrict__ Bt, int Kd, int Mblk,
    float* __restrict__ C, int ldc)
{
  __shared__ char smem[32768];
  short* Asm = (short*)smem;
  short* Bsm = (short*)(smem + 16384);
  int tid = threadIdx.x, lane = tid & 63, w = tid >> 6;
  int wr = w >> 1, wc = w & 1;
  int nwg = gridDim.x, bid = blockIdx.x;
  int sid = (bid & 7) * (nwg >> 3) + (bid >> 3);
  int row0 = (sid % Mblk) << 7;
  int col0 = (sid / Mblk) << 7;
  f32x4 acc[4][4];
  #pragma unroll
  for (int m=0;m<4;m++)
    #pragma unroll
    for (int nf=0;nf<4;nf++)
      #pragma unroll
      for (int e=0;e<4;e++) acc[m][nf][e] = 0.f;
  int lr8 = lane >> 3;
  int lk_sw = (((lane & 7) ^ (lane >> 3)) << 3);
  for (int k0 = 0; k0 < Kd; k0 += 64){
    #pragma unroll
    for (int i=0;i<4;i++){
      int chunk = (w<<2) + i;
      int r = (chunk<<3) + lr8;
      gload16(A  + (size_t)(row0 + r)*Kd + k0 + lk_sw, smem + chunk*1024);
      gload16(Bt + (size_t)(col0 + r)*Kd + k0 + lk_sw, smem + 16384 + chunk*1024);
    }
    __syncthreads();
    #pragma unroll
    for (int kk=0; kk<2; kk++){
      int csw = (kk*32 + ((lane>>4)<<3)) ^ ((lane & 7) << 3);
      s16x8 af[4], bfr[4];
      #pragma unroll
      for (int m=0;m<4;m++)
        af[m] = *(const s16x8*)(Asm + ((wr*64 + m*16 + (lane&15))*64 + csw));
      #pragma unroll
      for (int nf=0;nf<4;nf++)
        bfr[nf] = *(const s16x8*)(Bsm + ((wc*64 + nf*16 + (lane&15))*64 + csw));
      #pragma unroll
      for (int m=0;m<4;m++)
        #pragma unroll
        for (int nf=0;nf<4;nf++)
          acc[m][nf] = __builtin_amdgcn_mfma_f32_16x16x32_bf16(af[m], bfr[nf], acc[m][nf], 0, 0, 0);
    }
    __syncthreads();
  }
  #pragma unroll
  for (int m=0;m<4;m++)
    #pragma unroll
    for (int nf=0;nf<4;nf++)
      #pragma unroll
      for (int e=0;e<4;e++){
        int tok = wr*64 + m*16 + ((lane>>4)<<2) + e;
        int col = wc*64 + nf*16 + (lane&15);
        C[(size_t)(row0+tok)*ldc + col0 + col] = acc[m][nf][e];
      }
}

// ---------------- fused P-GEMM, 128x256 tile, MX-fp8 K=128, 2 blocks/CU, 3-phase ----------------
// C[c = r*32+n][tok] = B2f @ Xf8^T, fused n-contract -> Q/K bf16 + V^T.
// 8 waves (wm 0..1 x wn 0..3); phases q0=(rh0,ch0), q1=(rh1,ch0), q23={(rh1,ch1),(rh0,ch1)}.
// LDS 56 KiB: Ah0[2buf] @0/@8192, Ah1 @16384, Bh0 @24576, Bh1 @40960.
// 3-phase ledger (invariant: Ah1(kt)[1] outstanding at kt entry):
//  p0:  read Ah0,Bh0 [cert p23(kt-1)];  +Bh1(kt)[2];  VMC(2) certs Ah1(kt)
//  p1:  read Ah1 -> af1;                +Ah0(kt+1)[1]; VMC(1) certs Bh1(kt)
//  p23: read Bh1;                       +Bh0(kt+1)[2], +Ah1(kt+1)[1]; VMC(1) certs Ah0+Bh0(kt+1)
//       MFMA q2 (af1 x bf), q3 (af x bf)
#define STAGE_A(slotOff, arow0, tkt) do{ \
  int _t = (tkt) < 7 ? (tkt) : 7; \
  int _r = tid>>3, _g = tid&7; \
  gload16(B2f + (size_t)(row0 + (arow0) + _r)*1024 + (_t<<7) + ((_g ^ (_r&7))<<4), \
          smem + (slotOff) + (_r<<7) + (_g<<4)); \
}while(0)

#define STAGE_B(slotOff, trow0, tkt) do{ \
  int _t = (tkt) < 7 ? (tkt) : 7; \
  int _r = tid>>3, _g = tid&7; \
  gload16(Xf8 + (size_t)(col0 + (trow0) + _r)*1024 + (_t<<7) + ((_g ^ (_r&7))<<4), \
          smem + (slotOff) + (_r<<7) + (_g<<4)); \
  gload16(Xf8 + (size_t)(col0 + (trow0) + 64 + _r)*1024 + (_t<<7) + ((_g ^ (_r&7))<<4), \
          smem + (slotOff) + ((64+_r)<<7) + (_g<<4)); \
}while(0)

#define LD_AF(dst, base) \
  _Pragma("unroll") \
  for (int mi=0;mi<2;mi++){ \
    const char* _p = (base) + (wm*32 + mi*16 + l15)*128; \
    i32x4* _h = (i32x4*)&dst[mi]; \
    _h[0] = *(const i32x4*)(_p + ((ga0 ^ l7)<<4)); \
    _h[1] = *(const i32x4*)(_p + ((ga1 ^ l7)<<4)); \
  }

#define LD_BF(dst, base) \
  _Pragma("unroll") \
  for (int ni=0;ni<2;ni++){ \
    const char* _p = (base) + (wn*32 + ni*16 + l15)*128; \
    i32x4* _h = (i32x4*)&dst[ni]; \
    _h[0] = *(const i32x4*)(_p + ((ga0 ^ l7)<<4)); \
    _h[1] = *(const i32x4*)(_p + ((ga1 ^ l7)<<4)); \
  }

#define VMC(N) asm volatile("s_waitcnt vmcnt(" #N ")" ::: "memory")
#define PBAR() do{ __builtin_amdgcn_sched_barrier(0); __builtin_amdgcn_s_barrier(); }while(0)

#define MFMAP(Q, AF, BF) do{ \
  __builtin_amdgcn_s_setprio(1); \
  _Pragma("unroll") \
  for (int mi=0;mi<2;mi++) \
    _Pragma("unroll") \
    for (int ni=0;ni<2;ni++) \
      acc[Q][mi][ni] = __builtin_amdgcn_mfma_scale_f32_16x16x128_f8f6f4( \
          AF[mi], BF[ni], acc[Q][mi][ni], 0, 0, 0, 0x7f7f7f7f, 0, 0x7f7f7f7f); \
  __builtin_amdgcn_s_setprio(0); \
}while(0)

__global__ __launch_bounds__(512, 4) void k_pgemm8(
    const char* __restrict__ B2f, const char* __restrict__ Xf8,
    const float* __restrict__ tQp, const float* __restrict__ tKp, const float* __restrict__ tVp,
    short* __restrict__ Qb, short* __restrict__ Kb, short* __restrict__ Vt)
{
  extern __shared__ char smem[];
  int tid = threadIdx.x, lane = tid & 63, wid = tid >> 6;
  int wm = wid >> 2, wn = wid & 3;
  int l15 = lane & 15, l7 = lane & 7, g16 = lane >> 4;
  int ga0 = (g16 < 2) ? (g16 << 2) : (((g16 - 2) << 2) + 1);  // slot of k-granule 2*g16
  int ga1 = ga0 + 2;                                          // slot of k-granule 2*g16+1
  int bid = blockIdx.x;
  int xcd = bid & 7, lid = bid >> 3;        // lid 0..511
  int t_tile = (xcd << 2) + (lid & 3);      // 0..31
  int c_tile = lid >> 2;                    // 0..127
  int row0 = c_tile << 7;                   // B2f row base (128 rows)
  int col0 = t_tile << 8;                   // token base (256)

  f32x4 acc[4][2][2];                       // [phase-quadrant][mi][ni]
  #pragma unroll
  for (int q=0;q<4;q++)
    #pragma unroll
    for (int mi=0;mi<2;mi++)
      #pragma unroll
      for (int ni=0;ni<2;ni++)
        #pragma unroll
        for (int e=0;e<4;e++) acc[q][mi][ni][e] = 0.f;
  i32x8 af[2], af1[2], bf[2];

  // prologue: Ah0(0)@slot0, Bh0(0), Ah1(0); certify Ah0+Bh0; leaves Ah1(0)[1]
  STAGE_A(0, 0, 0);
  STAGE_B(24576, 0, 0);
  STAGE_A(16384, 64, 0);
  VMC(1);
  PBAR();

  for (int kt = 0; kt < 8; ++kt){
    const char* A0c = smem + ((kt&1)<<13);
    // ---- p0: q0 = (rh0, ch0) ----
    LD_AF(af, A0c);                          // Ah0(kt)  [certified]
    LD_BF(bf, smem + 24576);                 // Bh0(kt)  [certified]
    STAGE_B(40960, 128, kt);                 // Bh1(kt)
    VMC(2);                                  // certify Ah1(kt)
    PBAR();
    MFMAP(0, af, bf);
    // ---- p1: q1 = (rh1, ch0) ----
    LD_AF(af1, smem + 16384);                // Ah1(kt)  [certified]
    STAGE_A(((kt+1)&1)<<13, 0, kt+1);        // Ah0(kt+1) -> other slot
    VMC(1);                                  // certify Bh1(kt)
    PBAR();
    MFMAP(1, af1, bf);                       // Ah1 x Bh0(regs)
    // ---- p23: q2 = (rh1, ch1), q3 = (rh0, ch1) ----
    LD_BF(bf, smem + 40960);                 // Bh1(kt)  [certified]
    STAGE_B(24576, 0, kt+1);                 // Bh0(kt+1)
    STAGE_A(16384, 64, kt+1);                // Ah1(kt+1)
    VMC(1);                                  // certify Ah0(kt+1), Bh0(kt+1); leaves Ah1(kt+1)
    PBAR();
    MFMAP(2, af1, bf);                       // Ah1 x Bh1
    MFMAP(3, af, bf);                        // Ah0(regs) x Bh1
  }

  // ---- fused epilogue: Q/K[tok][r], V^T = sum_n C[r*32+n][tok]*t[tok][n] ----
  // phase q -> (rh,ch): q0=(0,0) q1=(1,0) q2=(1,1) q3=(0,1)
  VMC(0);
  __syncthreads();
  short* t16 = (short*)smem;    // [3][256 tok][36] bf16 = 27648 B
  for (int i2 = tid; i2 < 4096; i2 += 512){
    int tk = i2 >> 4, np = (i2 & 15) << 1;
    float2 a = *(const float2*)(tQp + (size_t)col0*32 + i2*2);
    float2 b = *(const float2*)(tKp + (size_t)col0*32 + i2*2);
    float2 c = *(const float2*)(tVp + (size_t)col0*32 + i2*2);
    *(int*)&t16[tk*36 + np]         = pack2bf(a.x, a.y);
    *(int*)&t16[9216 + tk*36 + np]  = pack2bf(b.x, b.y);
    *(int*)&t16[18432 + tk*36 + np] = pack2bf(c.x, c.y);
  }
  __syncthreads();
  int g4 = g16 << 2;
  #pragma unroll
  for (int rec=0; rec<3; rec++){
    const short* tb = t16 + rec*9216;
    #pragma unroll
    for (int q=0;q<4;q++){
      int rh = (q==1)||(q==2);
      int ch = q >> 1;
      int r = (c_tile << 2) + rh*2 + wm;
      #pragma unroll
      for (int ni=0;ni<2;ni++){
        int tok = ch*128 + wn*32 + ni*16 + l15;       // local token 0..255
        s16x4 tlo = *(const s16x4*)(tb + tok*36 + g4);
        s16x4 thi = *(const s16x4*)(tb + tok*36 + 16 + g4);
        float p = 0.f;
        #pragma unroll
        for (int e=0;e<4;e++) p += acc[q][0][ni][e] * bf2f(tlo[e]);
        #pragma unroll
        for (int e=0;e<4;e++) p += acc[q][1][ni][e] * bf2f(thi[e]);
        p += __shfl_xor(p, 16);
        p += __shfl_xor(p, 32);
        if (g16 == rec){
          int gtok = col0 + tok;
          if (rec == 0)      Qb[(size_t)gtok*512 + r] = f2bf(p);
          else if (rec == 1) Kb[(size_t)gtok*512 + r] = f2bf(p);
          else Vt[(((size_t)(gtok>>11)*8 + (r>>6))*64 + (r&63))*2048 + (gtok&2047)] = f2bf(p);
        }
      }
    }
  }
}

// ---------------- router: bf16-MFMA scores -> top-16 candidates -> f64 exact rescore -> top-8 ----------------
__global__ __launch_bounds__(64) void k_router(const float* __restrict__ scores,
    const float* __restrict__ X, const float* __restrict__ W,
    const float* __restrict__ rQ, const float* __restrict__ rK, const float* __restrict__ rV,
    float* __restrict__ tQ, float* __restrict__ tK, float* __restrict__ tV,
    float* __restrict__ oidx, float* __restrict__ ow){
  int token = blockIdx.x; int lane = threadIdx.x;
  const float* srow = scores + (size_t)token*512;
  float v[8];
  #pragma unroll
  for (int j=0;j<8;j++) v[j] = srow[lane + 64*j];
  int myidx = 0x7fffffff;
  #pragma unroll
  for (int k=0;k<16;k++){
    float bm = -INFINITY; int bi = 0x7fffffff;
    #pragma unroll
    for (int j=0;j<8;j++){ if (v[j] > bm) { bm = v[j]; bi = lane + 64*j; } }
    #pragma unroll
    for (int off=32; off>=1; off>>=1){
      float om = __shfl_xor(bm, off); int oi = __shfl_xor(bi, off);
      if (om > bm || (om == bm && oi < bi)) { bm = om; bi = oi; }
    }
    if (lane == k) myidx = bi;
    #pragma unroll
    for (int j=0;j<8;j++) if (lane + 64*j == bi) v[j] = -INFINITY;
  }
  float xr[16];
  {
    const float4* x4 = (const float4*)(X + (size_t)token*1024 + lane*16);
    #pragma unroll
    for (int q=0;q<4;q++){ float4 t = x4[q]; xr[q*4]=t.x; xr[q*4+1]=t.y; xr[q*4+2]=t.z; xr[q*4+3]=t.w; }
  }
  double myref = -1e300;
  #pragma unroll
  for (int c=0;c<16;c++){
    int nid = __shfl(myidx, c);
    const float4* w4 = (const float4*)(W + (size_t)nid*1024 + lane*16);
    double acc = 0.0;
    #pragma unroll
    for (int q=0;q<4;q++){
      float4 t = w4[q];
      acc += (double)xr[q*4]   * (double)t.x;
      acc += (double)xr[q*4+1] * (double)t.y;
      acc += (double)xr[q*4+2] * (double)t.z;
      acc += (double)xr[q*4+3] * (double)t.w;
    }
    #pragma unroll
    for (int off=32; off>=1; off>>=1) acc += __shfl_xor(acc, off);
    if (lane == c) myref = acc;
  }
  double mv = myref; int mi = myidx;
  double topv[8]; int topi[8];
  #pragma unroll
  for (int k=0;k<8;k++){
    double bm = mv; int bi = mi;
    #pragma unroll
    for (int off=32; off>=1; off>>=1){
      double om = __shfl_xor(bm, off); int oi = __shfl_xor(bi, off);
      if (om > bm || (om == bm && oi < bi)) { bm = om; bi = oi; }
    }
    topv[k]=bm; topi[k]=bi;
    if (mi == bi) mv = -1e300;
  }
  double mx = topv[0]; double s = 0.0; double wd[8];
  #pragma unroll
  for (int k=0;k<8;k++){ wd[k] = exp(topv[k]-mx); s += wd[k]; }
  float w[8];
  #pragma unroll
  for (int k=0;k<8;k++) w[k] = (float)(wd[k]/s);
  if (lane == 0){
    #pragma unroll
    for (int k=0;k<8;k++){ oidx[(size_t)token*8+k] = (float)topi[k]; ow[(size_t)token*8+k] = w[k]; }
  }
  int n = lane & 31;
  float aq=0.f, ak=0.f, av=0.f;
  #pragma unroll
  for (int k=0;k<8;k++){
    size_t off = (size_t)topi[k]*32 + n;
    aq += w[k]*rQ[off]; ak += w[k]*rK[off]; av += w[k]*rV[off];
  }
  float mq = aq, mk2 = ak, mvv = av;
  #pragma unroll
  for (int off=16; off>=1; off>>=1){
    mq  = fmaxf(mq,  __shfl_xor(mq, off));
    mk2 = fmaxf(mk2, __shfl_xor(mk2,off));
    mvv = fmaxf(mvv, __shfl_xor(mvv,off));
  }
  float eq = expf(aq-mq), ek = expf(ak-mk2), ev = expf(av-mvv);
  float sq = eq, sk = ek, sv = ev;
  #pragma unroll
  for (int off=16; off>=1; off>>=1){
    sq += __shfl_xor(sq,off); sk += __shfl_xor(sk,off); sv += __shfl_xor(sv,off);
  }
  if (lane < 32){
    tQ[(size_t)token*32+n] = eq/sq;
    tK[(size_t)token*32+n] = ek/sk;
    tV[(size_t)token*32+n] = ev/sv;
  }
}

// ---------------- causal flash attention: swapped-QK wave-parallel softmax ----------------
__global__ __launch_bounds__(256) void k_attn(const short* __restrict__ Qb, const short* __restrict__ Kb,
                                              const short* __restrict__ Vt, short* __restrict__ Ob)
{
  __shared__ char smem[40960];  // K[2][8KB] @0, Vt[2][8KB] @16384, P[4][2KB] @32768
  int tid = threadIdx.x, lane = tid & 63, wid = tid >> 6;
  int l15 = lane & 15, l7 = lane & 7, g16 = lane >> 4;
  int bid = blockIdx.x;
  int xcd = bid & 7, lid = bid >> 3;
  int work = xcd*128 + lid;              // XCD-chunked: 4 (b,h) per XCD
  int bx = 31 - (work & 31);             // big (diagonal-heavy) blocks first
  int bh = work >> 5; int h = bh & 7, b = bh >> 3;
  size_t tokbase = (size_t)b*2048;
  int q0 = bx << 6;
  int nt = bx + 1;
  const float SC = 0.125f * 1.44269504f; // scale folded with log2(e)

#define ATTN_STAGE(kt_) do{ \
  int _c = (kt_) & 1; \
  _Pragma("unroll") \
  for (int _i=0;_i<2;_i++){ \
    int _row = _i*32 + (wid<<3) + (lane>>3); \
    gload16(Kb + (tokbase + (((kt_)<<6) + _row))*512 + (h<<6) + ((l7 ^ (_row&7))<<3), \
            smem + (_c<<13) + _i*4096 + (wid<<10) + lane*16); \
    gload16(Vt + (size_t)((bh<<6) + _row)*2048 + ((kt_)<<6) + ((l7 ^ (_row&7))<<3), \
            smem + 16384 + (_c<<13) + _i*4096 + (wid<<10) + lane*16); \
  } \
}while(0)

  // Q fragments (B-operand rows = q)
  s16x8 qf[2];
  {
    const short* qp = Qb + (tokbase + q0 + wid*16 + l15)*512 + (h<<6);
    qf[0] = *(const s16x8*)(qp + g16*8);
    qf[1] = *(const s16x8*)(qp + 32 + g16*8);
  }
  int q_abs = q0 + wid*16 + l15;         // this lane's softmax row
  f32x4 o[4];
  float m_log = -INFINITY, l_sum = 0.f;
  #pragma unroll
  for (int i=0;i<4;i++)
    #pragma unroll
    for (int e=0;e<4;e++) o[i][e]=0.f;

  ATTN_STAGE(0);
  __syncthreads();

  for (int kt = 0; kt < nt; ++kt){
    if (kt + 1 < nt) ATTN_STAGE(kt+1);
    int cur = kt & 1;
    const char* Kc = smem + (cur<<13);
    const char* Vc = smem + 16384 + (cur<<13);
    char* Pb = smem + 32768 + (wid<<11);
    // ---- QK^T swapped: S[s16] rows = kv, cols = q ----
    f32x4 S[4];
    #pragma unroll
    for (int s16=0;s16<4;s16++){
      #pragma unroll
      for (int e=0;e<4;e++) S[s16][e] = 0.f;
      const char* kr = Kc + (s16*16 + l15)*128;
      s16x8 kf0 = *(const s16x8*)(kr + (((g16  ) ^ l7)<<4));
      s16x8 kf1 = *(const s16x8*)(kr + (((4+g16) ^ l7)<<4));
      S[s16] = __builtin_amdgcn_mfma_f32_16x16x32_bf16(kf0, qf[0], S[s16], 0,0,0);
      S[s16] = __builtin_amdgcn_mfma_f32_16x16x32_bf16(kf1, qf[1], S[s16], 0,0,0);
    }
    // ---- wave-parallel online softmax: lane owns full row q=l15 ----
    bool diag = (kt == nt-1);
    float sm[16];
    #pragma unroll
    for (int s16=0;s16<4;s16++)
      #pragma unroll
      for (int e=0;e<4;e++){
        float sv = S[s16][e] * SC;
        if (diag){
          int kv_abs = (kt<<6) + s16*16 + (g16<<2) + e;
          if (kv_abs > q_abs) sv = -1e30f;
        }
        sm[s16*4+e] = sv;
      }
    float pmax = sm[0];
    #pragma unroll
    for (int j=1;j<16;j++) pmax = fmaxf(pmax, sm[j]);
    pmax = fmaxf(pmax, __shfl_xor(pmax, 16));
    pmax = fmaxf(pmax, __shfl_xor(pmax, 32));
    float mnew = fmaxf(m_log, pmax);
    float alpha = exp2f(m_log - mnew);
    m_log = mnew;
    float p[16], ps = 0.f;
    #pragma unroll
    for (int j=0;j<16;j++){ p[j] = exp2f(sm[j] - mnew); ps += p[j]; }
    ps += __shfl_xor(ps, 16);
    ps += __shfl_xor(ps, 32);
    l_sum = l_sum*alpha + ps;
    #pragma unroll
    for (int e=0;e<4;e++){
      float al = __shfl(alpha, (g16<<2)+e);
      #pragma unroll
      for (int df=0;df<4;df++) o[df][e] *= al;
    }
    // ---- P -> LDS [q=l15][kv], XOR-swizzled 16B granules, 4x b64 writes ----
    #pragma unroll
    for (int s16=0;s16<4;s16++){
      s16x4 pk;
      #pragma unroll
      for (int e=0;e<4;e++) pk[e] = f2bf(p[s16*4+e]);
      *(s16x4*)(Pb + l15*128 + (((s16<<5) + (g16<<3)) ^ (l7<<4))) = pk;
    }
    // ---- PV: o += P(16q x 64kv) @ V^T(64d x 64kv)^T ----
    s16x8 pf0 = *(const s16x8*)(Pb + l15*128 + (((g16  ) ^ l7)<<4));
    s16x8 pf1 = *(const s16x8*)(Pb + l15*128 + (((4+g16) ^ l7)<<4));
    #pragma unroll
    for (int df=0;df<4;df++){
      const char* vr = Vc + (df*16 + l15)*128;
      s16x8 vf0 = *(const s16x8*)(vr + (((g16  ) ^ l7)<<4));
      s16x8 vf1 = *(const s16x8*)(vr + (((4+g16) ^ l7)<<4));
      o[df] = __builtin_amdgcn_mfma_f32_16x16x32_bf16(pf0, vf0, o[df], 0,0,0);
      o[df] = __builtin_amdgcn_mfma_f32_16x16x32_bf16(pf1, vf1, o[df], 0,0,0);
    }
    __syncthreads();
  }
  #pragma unroll
  for (int e=0;e<4;e++){
    float ln = __shfl(l_sum, (g16<<2)+e);
    float inv = 1.0f / ln;
    #pragma unroll
    for (int df=0;df<4;df++){
      int q = q0 + wid*16 + (g16<<2) + e;
      int d = df*16 + l15;
      Ob[(tokbase + q)*512 + (h<<6) + d] = f2bf(o[df][e] * inv);
    }
  }
#undef ATTN_STAGE
}

extern "C" void kernel_launch(void* const* d_in, const int* in_sizes, int n_in,
                              void* d_out, int out_size, void* d_ws, size_t ws_size,
                              hipStream_t stream)
{
  const float* x     = (const float*)d_in[0];
  const float* Wrt   = (const float*)d_in[1];
  const float* rQ    = (const float*)d_in[2];
  const float* rK    = (const float*)d_in[3];
  const float* rV    = (const float*)d_in[4];
  const float* basis = (const float*)d_in[5];
  const float* Wo    = (const float*)d_in[6];
  // d_in[7] = mask (causal tril; reproduced analytically)
  float* out = (float*)d_out;
  char* ws = (char*)d_ws;
  char*  B2f  = (char*)(ws + 0);           // 16 MB  [16384][1024] fp8 (slot-permuted)
  char*  Xf8  = (char*)(ws + 16777216);    // 8 MB   [8192][1024]  fp8 (slot-permuted)
  short* Xb   = (short*)(ws + 25165824);   // 16 MB  [8192][1024]  bf16
  float* SC   = (float*)(ws + 41943040);   // 16 MB  [8192][512]   f32
  float* tQ   = (float*)(ws + 58720256);   // 1 MB
  float* tK   = (float*)(ws + 59768832);   // 1 MB
  float* tV   = (float*)(ws + 60817408);   // 1 MB
  short* Qb   = (short*)(ws + 61865984);   // 8 MB   [8192][512] bf16
  short* Kb   = (short*)(ws + 70254592);   // 8 MB
  short* Vt   = (short*)(ws + 78643200);   // 8 MB   [4][8][64][2048] bf16 (V transposed)
  short* Ob   = (short*)(ws + 87031808);   // 8 MB
  short* Wob  = (short*)(ws + 95420416);   // 1 MB   [1024][512] bf16
  short* Wrtb = (short*)(ws + 96468992);   // 1 MB   [512][1024] bf16
  float* oidx = out + 8388608;
  float* oww  = out + 8454144;

  hipFuncSetAttribute((const void*)k_pgemm8, hipFuncAttributeMaxDynamicSharedMemorySize, 57344);

  k_conv_xw<<<3072, 256, 0, stream>>>(x, Xb, Xf8, Wo, Wrt, Wob, Wrtb);
  k_conv_basis8<<<dim3(8,16,32), 256, 0, stream>>>(basis, B2f);
  // scores: SC[8192][512] = Xb @ Wrtb^T (approx, bf16)
  k_gemm_c32<<<256, 256, 0, stream>>>(Xb, Wrtb, 1024, 64, SC, 512);
  k_router<<<8192, 64, 0, stream>>>(SC, x, Wrt, rQ, rK, rV, tQ, tK, tV, oidx, oww);
  k_pgemm8<<<4096, 512, 57344, stream>>>(B2f, Xf8, tQ, tK, tV, Qb, Kb, Vt);
  k_attn<<<1024, 256, 0, stream>>>(Qb, Kb, Vt, Ob);
  // out[8192][1024] = Ob @ Wob^T
  k_gemm_c32<<<512, 256, 0, stream>>>(Ob, Wob, 512, 64, out, 1024);
}

// Round 21
// 397.223 us; speedup vs baseline: 1.3419x; 1.3419x over previous
//
#include <hip/hip_runtime.h>
#include <math.h>
#include <stdint.h>

// Problem constants
// B=4 S=2048 D=1024 N_NEURONS=512 K=8 N_BASIS=32 R=512 H=8 dh=64
// tokens T = 8192

typedef __attribute__((ext_vector_type(4))) float f32x4;
typedef __attribute__((ext_vector_type(8))) short s16x8;
typedef __attribute__((ext_vector_type(4))) short s16x4;
typedef __attribute__((ext_vector_type(4))) int i32x4;
typedef __attribute__((ext_vector_type(8))) int i32x8;

#define DEV __device__ __forceinline__

DEV short f2bf(float f){
  union { float f; unsigned u; } c; c.f = f;
  unsigned u = c.u;
  unsigned r = (u + 0x7fffu + ((u >> 16) & 1u)) >> 16;
  return (short)r;
}
DEV float bf2f(short s){
  union { unsigned u; float f; } c; c.u = ((unsigned)(unsigned short)s) << 16;
  return c.f;
}
// f32 -> OCP e4m3fn (RNE, clamp to 448, subnormals to 2^-9 units)
DEV unsigned char f2e4m3(float f){
  union { float f; unsigned u; } c; c.f = f;
  unsigned u = c.u;
  unsigned sign = (u >> 24) & 0x80u;
  unsigned a = u & 0x7fffffffu;
  if (a >= 0x43e00000u) return (unsigned char)(sign | 0x7Eu);
  if (a < 0x3c800000u){
    union { unsigned u; float f; } d; d.u = a;
    int q = (int)(d.f * 512.0f + 0.5f);
    return (unsigned char)(sign | (unsigned)q);
  }
  unsigned m = a & 0x7fffffu;
  unsigned e = (a >> 23) - 120u;
  unsigned keep = m >> 20;
  unsigned rest = m & 0xFFFFFu;
  if (rest > 0x80000u || (rest == 0x80000u && (keep & 1u))){
    keep++;
    if (keep == 8u){ keep = 0; e++; }
  }
  if (e >= 16u || (e == 15u && keep == 7u)) return (unsigned char)(sign | 0x7Eu);
  return (unsigned char)(sign | (e << 3) | keep);
}

typedef __attribute__((address_space(3))) void lds_vt;
typedef const __attribute__((address_space(1))) void g_vt;
DEV void gload16(const void* g, void* lds){
  __builtin_amdgcn_global_load_lds((g_vt*)g, (lds_vt*)lds, 16, 0, 0);
}

// K-granule slot permutation within each 128B k-group (applied to BOTH operands
// -> k-relabeling, sum invariant). slot(c) = c<4 ? 2c : 2(c-4)+1.
DEV int gslot(int c){ return (c < 4) ? (c << 1) : (((c - 4) << 1) + 1); }

// ---------------- fused conversions: x -> {Xb bf16, Xf8 fp8 slot-permuted}; Wo,Wrt -> bf16 ----------------
__global__ void k_conv_xw(const float* __restrict__ x, short* __restrict__ Xb, char* __restrict__ Xf8,
                          const float* __restrict__ Wo, const float* __restrict__ Wrt,
                          short* __restrict__ Wob, short* __restrict__ Wrtb){
  int t = blockIdx.x*256 + threadIdx.x;   // 786432 tasks
  if (t < 524288){
    size_t d = (size_t)t * 16;
    const float4* s = (const float4*)(x + d);
    float vals[16];
    #pragma unroll
    for (int q=0;q<4;q++){ float4 v = s[q]; vals[q*4]=v.x; vals[q*4+1]=v.y; vals[q*4+2]=v.z; vals[q*4+3]=v.w; }
    s16x8 ob0, ob1;
    unsigned long long v0 = 0, v1 = 0;
    #pragma unroll
    for (int e=0;e<8;e++){
      ob0[e] = f2bf(vals[e]);
      ob1[e] = f2bf(vals[8+e]);
      v0 |= ((unsigned long long)f2e4m3(vals[e]))   << (8*e);
      v1 |= ((unsigned long long)f2e4m3(vals[8+e])) << (8*e);
    }
    *(s16x8*)(Xb + d) = ob0;
    *(s16x8*)(Xb + d + 8) = ob1;
    int c = t & 7;
    char* dst = Xf8 + (d & ~(size_t)127) + (gslot(c) << 4);
    *(unsigned long long*)dst = v0;
    *(unsigned long long*)(dst + 8) = v1;
  } else {
    int i = t - 524288;                   // 262144 float4 tasks
    const float* src = (i < 131072) ? Wo : Wrt;
    short* dst = (i < 131072) ? Wob : Wrtb;
    int j = (i < 131072) ? i : (i - 131072);
    float4 v = ((const float4*)src)[j];
    s16x4 o; o[0]=f2bf(v.x); o[1]=f2bf(v.y); o[2]=f2bf(v.z); o[3]=f2bf(v.w);
    ((s16x4*)dst)[j] = o;
  }
}

// ---------------- basis [32][1024][512] -> B2f fp8 [16384][1024], row c=r*32+n, slot-permuted ----------------
__global__ __launch_bounds__(256) void k_conv_basis8(const float* __restrict__ basis, char* __restrict__ B2f){
  __shared__ float tile[64][65];
  int tid = threadIdx.x;
  int r0 = blockIdx.x<<6, d0 = blockIdx.y<<6, n = blockIdx.z;
  const float* src = basis + ((size_t)n*1024 + d0)*512 + r0;
  for (int i = tid; i < 4096; i += 256){ int dd = i>>6, rr = i&63; tile[dd][rr] = src[(size_t)dd*512 + rr]; }
  __syncthreads();
  int rr = tid >> 2, j = tid & 3;
  unsigned long long v0 = 0, v1 = 0;
  #pragma unroll
  for (int e=0;e<8;e++){
    v0 |= ((unsigned long long)f2e4m3(tile[j*16+e][rr]))   << (8*e);
    v1 |= ((unsigned long long)f2e4m3(tile[j*16+8+e][rr])) << (8*e);
  }
  int c = j + ((d0 >> 4) & 4);
  char* dst = B2f + ((size_t)(r0+rr)*32 + n)*1024 + (size_t)(d0 & ~127) + (gslot(c) << 4);
  *(unsigned long long*)dst = v0;
  *(unsigned long long*)(dst + 8) = v1;
}

// ---------------- bf16 MFMA GEMM 128x128xBK64 -> f32 C (scores, W_o) ----------------
__global__ __launch_bounds__(256) void k_gemm_c32(
    const short* __restrict__ A, const short* __restrict__ Bt, int Kd, int Mblk,
    float* __restrict__ C, int ldc)
{
  __shared__ char smem[32768];
  short* Asm = (short*)smem;
  short* Bsm = (short*)(smem + 16384);
  int tid = threadIdx.x, lane = tid & 63, w = tid >> 6;
  int wr = w >> 1, wc = w & 1;
  int nwg = gridDim.x, bid = blockIdx.x;
  int sid = (bid & 7) * (nwg >> 3) + (bid >> 3);
  int row0 = (sid % Mblk) << 7;
  int col0 = (sid / Mblk) << 7;
  f32x4 acc[4][4];
  #pragma unroll
  for (int m=0;m<4;m++)
    #pragma unroll
    for (int nf=0;nf<4;nf++)
      #pragma unroll
      for (int e=0;e<4;e++) acc[m][nf][e] = 0.f;
  int lr8 = lane >> 3;
  int lk_sw = (((lane & 7) ^ (lane >> 3)) << 3);
  for (int k0 = 0; k0 < Kd; k0 += 64){
    #pragma unroll
    for (int i=0;i<4;i++){
      int chunk = (w<<2) + i;
      int r = (chunk<<3) + lr8;
      gload16(A  + (size_t)(row0 + r)*Kd + k0 + lk_sw, smem + chunk*1024);
      gload16(Bt + (size_t)(col0 + r)*Kd + k0 + lk_sw, smem + 16384 + chunk*1024);
    }
    __syncthreads();
    #pragma unroll
    for (int kk=0; kk<2; kk++){
      int csw = (kk*32 + ((lane>>4)<<3)) ^ ((lane & 7) << 3);
      s16x8 af[4], bfr[4];
      #pragma unroll
      for (int m=0;m<4;m++)
        af[m] = *(const s16x8*)(Asm + ((wr*64 + m*16 + (lane&15))*64 + csw));
      #pragma unroll
      for (int nf=0;nf<4;nf++)
        bfr[nf] = *(const s16x8*)(Bsm + ((wc*64 + nf*16 + (lane&15))*64 + csw));
      #pragma unroll
      for (int m=0;m<4;m++)
        #pragma unroll
        for (int nf=0;nf<4;nf++)
          acc[m][nf] = __builtin_amdgcn_mfma_f32_16x16x32_bf16(af[m], bfr[nf], acc[m][nf], 0, 0, 0);
    }
    __syncthreads();
  }
  #pragma unroll
  for (int m=0;m<4;m++)
    #pragma unroll
    for (int nf=0;nf<4;nf++)
      #pragma unroll
      for (int e=0;e<4;e++){
        int tok = wr*64 + m*16 + ((lane>>4)<<2) + e;
        int col = wc*64 + nf*16 + (lane&15);
        C[(size_t)(row0+tok)*ldc + col0 + col] = acc[m][nf][e];
      }
}

// ---------------- fused P-GEMM, 128x256 tile, MX-fp8 K=128, 2 blocks/CU (R17 version) ----------------
#define STAGE_A(slotOff, arow0, tkt) do{ \
  int _t = (tkt) < 7 ? (tkt) : 7; \
  int _r = tid>>3, _g = tid&7; \
  gload16(B2f + (size_t)(row0 + (arow0) + _r)*1024 + (_t<<7) + ((_g ^ (_r&7))<<4), \
          smem + (slotOff) + (_r<<7) + (_g<<4)); \
}while(0)

#define STAGE_B(slotOff, trow0, tkt) do{ \
  int _t = (tkt) < 7 ? (tkt) : 7; \
  int _r = tid>>3, _g = tid&7; \
  gload16(Xf8 + (size_t)(col0 + (trow0) + _r)*1024 + (_t<<7) + ((_g ^ (_r&7))<<4), \
          smem + (slotOff) + (_r<<7) + (_g<<4)); \
  gload16(Xf8 + (size_t)(col0 + (trow0) + 64 + _r)*1024 + (_t<<7) + ((_g ^ (_r&7))<<4), \
          smem + (slotOff) + ((64+_r)<<7) + (_g<<4)); \
}while(0)

#define LD_AF(dst, base) \
  _Pragma("unroll") \
  for (int mi=0;mi<2;mi++){ \
    const char* _p = (base) + (wm*32 + mi*16 + l15)*128; \
    i32x4* _h = (i32x4*)&dst[mi]; \
    _h[0] = *(const i32x4*)(_p + ((ga0 ^ l7)<<4)); \
    _h[1] = *(const i32x4*)(_p + ((ga1 ^ l7)<<4)); \
  }

#define LD_BF(dst, base) \
  _Pragma("unroll") \
  for (int ni=0;ni<2;ni++){ \
    const char* _p = (base) + (wn*32 + ni*16 + l15)*128; \
    i32x4* _h = (i32x4*)&dst[ni]; \
    _h[0] = *(const i32x4*)(_p + ((ga0 ^ l7)<<4)); \
    _h[1] = *(const i32x4*)(_p + ((ga1 ^ l7)<<4)); \
  }

#define VMC(N) asm volatile("s_waitcnt vmcnt(" #N ")" ::: "memory")
#define PBAR() do{ __builtin_amdgcn_sched_barrier(0); __builtin_amdgcn_s_barrier(); }while(0)

#define MFMAP(Q, AF, BF) do{ \
  __builtin_amdgcn_s_setprio(1); \
  _Pragma("unroll") \
  for (int mi=0;mi<2;mi++) \
    _Pragma("unroll") \
    for (int ni=0;ni<2;ni++) \
      acc[Q][mi][ni] = __builtin_amdgcn_mfma_scale_f32_16x16x128_f8f6f4( \
          AF[mi], BF[ni], acc[Q][mi][ni], 0, 0, 0, 0x7f7f7f7f, 0, 0x7f7f7f7f); \
  __builtin_amdgcn_s_setprio(0); \
}while(0)

__global__ __launch_bounds__(512, 4) void k_pgemm8(
    const char* __restrict__ B2f, const char* __restrict__ Xf8,
    const float* __restrict__ tQp, const float* __restrict__ tKp, const float* __restrict__ tVp,
    short* __restrict__ Qb, short* __restrict__ Kb, short* __restrict__ Vt)
{
  extern __shared__ char smem[];
  int tid = threadIdx.x, lane = tid & 63, wid = tid >> 6;
  int wm = wid >> 2, wn = wid & 3;
  int l15 = lane & 15, l7 = lane & 7, g16 = lane >> 4;
  int ga0 = (g16 < 2) ? (g16 << 2) : (((g16 - 2) << 2) + 1);  // slot of k-granule 2*g16
  int ga1 = ga0 + 2;                                          // slot of k-granule 2*g16+1
  int bid = blockIdx.x;
  int xcd = bid & 7, lid = bid >> 3;        // lid 0..511
  int t_tile = (xcd << 2) + (lid & 3);      // 0..31
  int c_tile = lid >> 2;                    // 0..127
  int row0 = c_tile << 7;                   // B2f row base (128 rows)
  int col0 = t_tile << 8;                   // token base (256)

  f32x4 acc[4][2][2];                       // [phase-quadrant][mi][ni]
  #pragma unroll
  for (int q=0;q<4;q++)
    #pragma unroll
    for (int mi=0;mi<2;mi++)
      #pragma unroll
      for (int ni=0;ni<2;ni++)
        #pragma unroll
        for (int e=0;e<4;e++) acc[q][mi][ni][e] = 0.f;
  i32x8 af[2], bf[2];

  // prologue: Ah0(0)@slot0, Bh0(0), Ah1(0); certify Ah0+Bh0 for p0's reads
  STAGE_A(0, 0, 0);
  STAGE_B(24576, 0, 0);
  STAGE_A(16384, 64, 0);
  VMC(1);
  PBAR();

  for (int kt = 0; kt < 8; ++kt){
    const char* A0c = smem + ((kt&1)<<13);
    // ---- p0: q0 = (rh0, ch0) ----
    LD_AF(af, A0c);                          // Ah0(kt)  [certified]
    LD_BF(bf, smem + 24576);                 // Bh0(kt)  [certified]
    STAGE_B(40960, 128, kt);                 // Bh1(kt)
    VMC(2);                                  // certify Ah1(kt)
    PBAR();
    MFMAP(0, af, bf);
    // ---- p1: q1 = (rh1, ch0) ----
    LD_AF(af, smem + 16384);                 // Ah1(kt)  [certified]
    STAGE_A(((kt+1)&1)<<13, 0, kt+1);        // Ah0(kt+1) -> other slot
    VMC(1);                                  // certify Bh1(kt)
    PBAR();
    MFMAP(1, af, bf);                        // Ah1 x Bh0(regs)
    // ---- p2: q2 = (rh1, ch1) ----
    LD_BF(bf, smem + 40960);                 // Bh1(kt)  [certified]
    STAGE_B(24576, 0, kt+1);                 // Bh0(kt+1)
    PBAR();                                  // no VMC (p3 reads already certified)
    MFMAP(2, af, bf);                        // Ah1(regs) x Bh1
    // ---- p3: q3 = (rh0, ch1) ----
    LD_AF(af, A0c);                          // Ah0(kt) reload [certified]
    STAGE_A(16384, 64, kt+1);                // Ah1(kt+1)
    VMC(1);                                  // certify Ah0(kt+1), Bh0(kt+1)
    PBAR();
    MFMAP(3, af, bf);                        // Ah0 x Bh1(regs)
  }

  // ---- fused epilogue: Q/K[tok][r], V^T = sum_n C[r*32+n][tok]*t[tok][n] ----
  // phase q -> (rh,ch): q0=(0,0) q1=(1,0) q2=(1,1) q3=(0,1)
  VMC(0);
  __syncthreads();
  short* t16 = (short*)smem;    // [3][256 tok][36] bf16 = 27648 B
  for (int i = tid; i < 8192; i += 512){
    int tk = i >> 5, n = i & 31;
    t16[tk*36 + n]            = f2bf(tQp[(size_t)col0*32 + i]);
    t16[9216 + tk*36 + n]     = f2bf(tKp[(size_t)col0*32 + i]);
    t16[18432 + tk*36 + n]    = f2bf(tVp[(size_t)col0*32 + i]);
  }
  __syncthreads();
  int g4 = g16 << 2;
  #pragma unroll
  for (int rec=0; rec<3; rec++){
    const short* tb = t16 + rec*9216;
    #pragma unroll
    for (int q=0;q<4;q++){
      int rh = (q==1)||(q==2);
      int ch = q >> 1;
      int r = (c_tile << 2) + rh*2 + wm;
      #pragma unroll
      for (int ni=0;ni<2;ni++){
        int tok = ch*128 + wn*32 + ni*16 + l15;       // local token 0..255
        s16x4 tlo = *(const s16x4*)(tb + tok*36 + g4);
        s16x4 thi = *(const s16x4*)(tb + tok*36 + 16 + g4);
        float p = 0.f;
        #pragma unroll
        for (int e=0;e<4;e++) p += acc[q][0][ni][e] * bf2f(tlo[e]);
        #pragma unroll
        for (int e=0;e<4;e++) p += acc[q][1][ni][e] * bf2f(thi[e]);
        p += __shfl_xor(p, 16);
        p += __shfl_xor(p, 32);
        if (g16 == rec){
          int gtok = col0 + tok;
          if (rec == 0)      Qb[(size_t)gtok*512 + r] = f2bf(p);
          else if (rec == 1) Kb[(size_t)gtok*512 + r] = f2bf(p);
          else Vt[(((size_t)(gtok>>11)*8 + (r>>6))*64 + (r&63))*2048 + (gtok&2047)] = f2bf(p);
        }
      }
    }
  }
}

// ---------------- router: bf16-MFMA scores -> top-16 candidates -> f64 exact rescore -> top-8 ----------------
__global__ __launch_bounds__(64) void k_router(const float* __restrict__ scores,
    const float* __restrict__ X, const float* __restrict__ W,
    const float* __restrict__ rQ, const float* __restrict__ rK, const float* __restrict__ rV,
    float* __restrict__ tQ, float* __restrict__ tK, float* __restrict__ tV,
    float* __restrict__ oidx, float* __restrict__ ow){
  int token = blockIdx.x; int lane = threadIdx.x;
  const float* srow = scores + (size_t)token*512;
  float v[8];
  #pragma unroll
  for (int j=0;j<8;j++) v[j] = srow[lane + 64*j];
  int myidx = 0x7fffffff;
  #pragma unroll
  for (int k=0;k<16;k++){
    float bm = -INFINITY; int bi = 0x7fffffff;
    #pragma unroll
    for (int j=0;j<8;j++){ if (v[j] > bm) { bm = v[j]; bi = lane + 64*j; } }
    #pragma unroll
    for (int off=32; off>=1; off>>=1){
      float om = __shfl_xor(bm, off); int oi = __shfl_xor(bi, off);
      if (om > bm || (om == bm && oi < bi)) { bm = om; bi = oi; }
    }
    if (lane == k) myidx = bi;
    #pragma unroll
    for (int j=0;j<8;j++) if (lane + 64*j == bi) v[j] = -INFINITY;
  }
  float xr[16];
  {
    const float4* x4 = (const float4*)(X + (size_t)token*1024 + lane*16);
    #pragma unroll
    for (int q=0;q<4;q++){ float4 t = x4[q]; xr[q*4]=t.x; xr[q*4+1]=t.y; xr[q*4+2]=t.z; xr[q*4+3]=t.w; }
  }
  double myref = -1e300;
  #pragma unroll
  for (int c=0;c<16;c++){
    int nid = __shfl(myidx, c);
    const float4* w4 = (const float4*)(W + (size_t)nid*1024 + lane*16);
    double acc = 0.0;
    #pragma unroll
    for (int q=0;q<4;q++){
      float4 t = w4[q];
      acc += (double)xr[q*4]   * (double)t.x;
      acc += (double)xr[q*4+1] * (double)t.y;
      acc += (double)xr[q*4+2] * (double)t.z;
      acc += (double)xr[q*4+3] * (double)t.w;
    }
    #pragma unroll
    for (int off=32; off>=1; off>>=1) acc += __shfl_xor(acc, off);
    if (lane == c) myref = acc;
  }
  double mv = myref; int mi = myidx;
  double topv[8]; int topi[8];
  #pragma unroll
  for (int k=0;k<8;k++){
    double bm = mv; int bi = mi;
    #pragma unroll
    for (int off=32; off>=1; off>>=1){
      double om = __shfl_xor(bm, off); int oi = __shfl_xor(bi, off);
      if (om > bm || (om == bm && oi < bi)) { bm = om; bi = oi; }
    }
    topv[k]=bm; topi[k]=bi;
    if (mi == bi) mv = -1e300;
  }
  double mx = topv[0]; double s = 0.0; double wd[8];
  #pragma unroll
  for (int k=0;k<8;k++){ wd[k] = exp(topv[k]-mx); s += wd[k]; }
  float w[8];
  #pragma unroll
  for (int k=0;k<8;k++) w[k] = (float)(wd[k]/s);
  if (lane == 0){
    #pragma unroll
    for (int k=0;k<8;k++){ oidx[(size_t)token*8+k] = (float)topi[k]; ow[(size_t)token*8+k] = w[k]; }
  }
  int n = lane & 31;
  float aq=0.f, ak=0.f, av=0.f;
  #pragma unroll
  for (int k=0;k<8;k++){
    size_t off = (size_t)topi[k]*32 + n;
    aq += w[k]*rQ[off]; ak += w[k]*rK[off]; av += w[k]*rV[off];
  }
  float mq = aq, mk2 = ak, mvv = av;
  #pragma unroll
  for (int off=16; off>=1; off>>=1){
    mq  = fmaxf(mq,  __shfl_xor(mq, off));
    mk2 = fmaxf(mk2, __shfl_xor(mk2,off));
    mvv = fmaxf(mvv, __shfl_xor(mvv,off));
  }
  float eq = expf(aq-mq), ek = expf(ak-mk2), ev = expf(av-mvv);
  float sq = eq, sk = ek, sv = ev;
  #pragma unroll
  for (int off=16; off>=1; off>>=1){
    sq += __shfl_xor(sq,off); sk += __shfl_xor(sk,off); sv += __shfl_xor(sv,off);
  }
  if (lane < 32){
    tQ[(size_t)token*32+n] = eq/sq;
    tK[(size_t)token*32+n] = ek/sk;
    tV[(size_t)token*32+n] = ev/sv;
  }
}

// ---------------- causal flash attention: swapped-QK wave-parallel softmax ----------------
__global__ __launch_bounds__(256) void k_attn(const short* __restrict__ Qb, const short* __restrict__ Kb,
                                              const short* __restrict__ Vt, short* __restrict__ Ob)
{
  __shared__ char smem[40960];  // K[2][8KB] @0, Vt[2][8KB] @16384, P[4][2KB] @32768
  int tid = threadIdx.x, lane = tid & 63, wid = tid >> 6;
  int l15 = lane & 15, l7 = lane & 7, g16 = lane >> 4;
  int bid = blockIdx.x;
  int xcd = bid & 7, lid = bid >> 3;
  int work = xcd*128 + lid;              // XCD-chunked: 4 (b,h) per XCD
  int bx = 31 - (work & 31);             // big (diagonal-heavy) blocks first
  int bh = work >> 5; int h = bh & 7, b = bh >> 3;
  size_t tokbase = (size_t)b*2048;
  int q0 = bx << 6;
  int nt = bx + 1;
  const float SC = 0.125f * 1.44269504f; // scale folded with log2(e)

#define ATTN_STAGE(kt_) do{ \
  int _c = (kt_) & 1; \
  _Pragma("unroll") \
  for (int _i=0;_i<2;_i++){ \
    int _row = _i*32 + (wid<<3) + (lane>>3); \
    gload16(Kb + (tokbase + (((kt_)<<6) + _row))*512 + (h<<6) + ((l7 ^ (_row&7))<<3), \
            smem + (_c<<13) + _i*4096 + (wid<<10) + lane*16); \
    gload16(Vt + (size_t)((bh<<6) + _row)*2048 + ((kt_)<<6) + ((l7 ^ (_row&7))<<3), \
            smem + 16384 + (_c<<13) + _i*4096 + (wid<<10) + lane*16); \
  } \
}while(0)

  // Q fragments (B-operand rows = q)
  s16x8 qf[2];
  {
    const short* qp = Qb + (tokbase + q0 + wid*16 + l15)*512 + (h<<6);
    qf[0] = *(const s16x8*)(qp + g16*8);
    qf[1] = *(const s16x8*)(qp + 32 + g16*8);
  }
  int q_abs = q0 + wid*16 + l15;         // this lane's softmax row
  f32x4 o[4];
  float m_log = -INFINITY, l_sum = 0.f;
  #pragma unroll
  for (int i=0;i<4;i++)
    #pragma unroll
    for (int e=0;e<4;e++) o[i][e]=0.f;

  ATTN_STAGE(0);
  __syncthreads();

  for (int kt = 0; kt < nt; ++kt){
    if (kt + 1 < nt) ATTN_STAGE(kt+1);
    int cur = kt & 1;
    const char* Kc = smem + (cur<<13);
    const char* Vc = smem + 16384 + (cur<<13);
    char* Pb = smem + 32768 + (wid<<11);
    // ---- QK^T swapped: S[s16] rows = kv, cols = q ----
    f32x4 S[4];
    #pragma unroll
    for (int s16=0;s16<4;s16++){
      #pragma unroll
      for (int e=0;e<4;e++) S[s16][e] = 0.f;
      const char* kr = Kc + (s16*16 + l15)*128;
      s16x8 kf0 = *(const s16x8*)(kr + (((g16  ) ^ l7)<<4));
      s16x8 kf1 = *(const s16x8*)(kr + (((4+g16) ^ l7)<<4));
      S[s16] = __builtin_amdgcn_mfma_f32_16x16x32_bf16(kf0, qf[0], S[s16], 0,0,0);
      S[s16] = __builtin_amdgcn_mfma_f32_16x16x32_bf16(kf1, qf[1], S[s16], 0,0,0);
    }
    // ---- wave-parallel online softmax: lane owns full row q=l15 ----
    bool diag = (kt == nt-1);
    float sm[16];
    #pragma unroll
    for (int s16=0;s16<4;s16++)
      #pragma unroll
      for (int e=0;e<4;e++){
        float sv = S[s16][e] * SC;
        if (diag){
          int kv_abs = (kt<<6) + s16*16 + (g16<<2) + e;
          if (kv_abs > q_abs) sv = -1e30f;
        }
        sm[s16*4+e] = sv;
      }
    float pmax = sm[0];
    #pragma unroll
    for (int j=1;j<16;j++) pmax = fmaxf(pmax, sm[j]);
    pmax = fmaxf(pmax, __shfl_xor(pmax, 16));
    pmax = fmaxf(pmax, __shfl_xor(pmax, 32));
    float mnew = fmaxf(m_log, pmax);
    float alpha = exp2f(m_log - mnew);
    m_log = mnew;
    float p[16], ps = 0.f;
    #pragma unroll
    for (int j=0;j<16;j++){ p[j] = exp2f(sm[j] - mnew); ps += p[j]; }
    ps += __shfl_xor(ps, 16);
    ps += __shfl_xor(ps, 32);
    l_sum = l_sum*alpha + ps;
    #pragma unroll
    for (int e=0;e<4;e++){
      float al = __shfl(alpha, (g16<<2)+e);
      #pragma unroll
      for (int df=0;df<4;df++) o[df][e] *= al;
    }
    // ---- P -> LDS [q=l15][kv], XOR-swizzled 16B granules, 4x b64 writes ----
    #pragma unroll
    for (int s16=0;s16<4;s16++){
      s16x4 pk;
      #pragma unroll
      for (int e=0;e<4;e++) pk[e] = f2bf(p[s16*4+e]);
      *(s16x4*)(Pb + l15*128 + (((s16<<5) + (g16<<3)) ^ (l7<<4))) = pk;
    }
    // ---- PV: o += P(16q x 64kv) @ V^T(64d x 64kv)^T ----
    s16x8 pf0 = *(const s16x8*)(Pb + l15*128 + (((g16  ) ^ l7)<<4));
    s16x8 pf1 = *(const s16x8*)(Pb + l15*128 + (((4+g16) ^ l7)<<4));
    #pragma unroll
    for (int df=0;df<4;df++){
      const char* vr = Vc + (df*16 + l15)*128;
      s16x8 vf0 = *(const s16x8*)(vr + (((g16  ) ^ l7)<<4));
      s16x8 vf1 = *(const s16x8*)(vr + (((4+g16) ^ l7)<<4));
      o[df] = __builtin_amdgcn_mfma_f32_16x16x32_bf16(pf0, vf0, o[df], 0,0,0);
      o[df] = __builtin_amdgcn_mfma_f32_16x16x32_bf16(pf1, vf1, o[df], 0,0,0);
    }
    __syncthreads();
  }
  #pragma unroll
  for (int e=0;e<4;e++){
    float ln = __shfl(l_sum, (g16<<2)+e);
    float inv = 1.0f / ln;
    #pragma unroll
    for (int df=0;df<4;df++){
      int q = q0 + wid*16 + (g16<<2) + e;
      int d = df*16 + l15;
      Ob[(tokbase + q)*512 + (h<<6) + d] = f2bf(o[df][e] * inv);
    }
  }
#undef ATTN_STAGE
}

extern "C" void kernel_launch(void* const* d_in, const int* in_sizes, int n_in,
                              void* d_out, int out_size, void* d_ws, size_t ws_size,
                              hipStream_t stream)
{
  const float* x     = (const float*)d_in[0];
  const float* Wrt   = (const float*)d_in[1];
  const float* rQ    = (const float*)d_in[2];
  const float* rK    = (const float*)d_in[3];
  const float* rV    = (const float*)d_in[4];
  const float* basis = (const float*)d_in[5];
  const float* Wo    = (const float*)d_in[6];
  // d_in[7] = mask (causal tril; reproduced analytically)
  float* out = (float*)d_out;
  char* ws = (char*)d_ws;
  char*  B2f  = (char*)(ws + 0);           // 16 MB  [16384][1024] fp8 (slot-permuted)
  char*  Xf8  = (char*)(ws + 16777216);    // 8 MB   [8192][1024]  fp8 (slot-permuted)
  short* Xb   = (short*)(ws + 25165824);   // 16 MB  [8192][1024]  bf16
  float* SC   = (float*)(ws + 41943040);   // 16 MB  [8192][512]   f32
  float* tQ   = (float*)(ws + 58720256);   // 1 MB
  float* tK   = (float*)(ws + 59768832);   // 1 MB
  float* tV   = (float*)(ws + 60817408);   // 1 MB
  short* Qb   = (short*)(ws + 61865984);   // 8 MB   [8192][512] bf16
  short* Kb   = (short*)(ws + 70254592);   // 8 MB
  short* Vt   = (short*)(ws + 78643200);   // 8 MB   [4][8][64][2048] bf16 (V transposed)
  short* Ob   = (short*)(ws + 87031808);   // 8 MB
  short* Wob  = (short*)(ws + 95420416);   // 1 MB   [1024][512] bf16
  short* Wrtb = (short*)(ws + 96468992);   // 1 MB   [512][1024] bf16
  float* oidx = out + 8388608;
  float* oww  = out + 8454144;

  hipFuncSetAttribute((const void*)k_pgemm8, hipFuncAttributeMaxDynamicSharedMemorySize, 57344);

  k_conv_xw<<<3072, 256, 0, stream>>>(x, Xb, Xf8, Wo, Wrt, Wob, Wrtb);
  k_conv_basis8<<<dim3(8,16,32), 256, 0, stream>>>(basis, B2f);
  // scores: SC[8192][512] = Xb @ Wrtb^T (approx, bf16)
  k_gemm_c32<<<256, 256, 0, stream>>>(Xb, Wrtb, 1024, 64, SC, 512);
  k_router<<<8192, 64, 0, stream>>>(SC, x, Wrt, rQ, rK, rV, tQ, tK, tV, oidx, oww);
  k_pgemm8<<<4096, 512, 57344, stream>>>(B2f, Xf8, tQ, tK, tV, Qb, Kb, Vt);
  k_attn<<<1024, 256, 0, stream>>>(Qb, Kb, Vt, Ob);
  // out[8192][1024] = Ob @ Wob^T
  k_gemm_c32<<<512, 256, 0, stream>>>(Ob, Wob, 512, 64, out, 1024);
}